// Round 8
// baseline (215.917 us; speedup 1.0000x reference)
//
#include <hip/hip_runtime.h>
#include <math.h>

// Problem constants (fixed by setup_inputs)
#define B_  4
#define C_  256
#define W_  64
#define M_  4096          // ref locations (H*W)
#define N_  4096          // anchors per batch (== M_)
#define THRESH_ 0.4f      // relu(0.6 - dist) = relu(sim - 0.4)

typedef __attribute__((ext_vector_type(8))) short bf16x8;
typedef __attribute__((ext_vector_type(4))) float f32x4;

__device__ __forceinline__ short f2bf(float x) {       // RNE float->bf16
    union { float f; unsigned u; } v; v.f = x;
    unsigned r = v.u + 0x7fffu + ((v.u >> 16) & 1u);
    return (short)(r >> 16);
}
__device__ __forceinline__ float bf2f(short s) {
    union { unsigned u; float f; } v;
    v.u = ((unsigned)(unsigned short)s) << 16;
    return v.f;
}
__device__ __forceinline__ void gload_lds16(const void* g, void* l) {
    __builtin_amdgcn_global_load_lds(
        (const __attribute__((address_space(1))) void*)g,
        (__attribute__((address_space(3))) void*)l, 16, 0, 0);
}

// ---------------------------------------------------------------------------
// Workspace layout (bytes); total = 17,432,576 == r5-proven bound.
//   sketchT (bf16) : B*M*C*2 = 8,388,608   [b][m][c]
//   refT    (bf16) : B*M*C*2 = 8,388,608   [b][m][c]
//   isn            :    65,536   1/||sketch col||
//   ir             :    65,536   1/||ref col||
//   ssum           :   262,144   4 sections [z*2+chalf][b*M+m]
//   diag           :    65,536   (gemm-written; disjoint from ssum)
//   rowsum         :    65,536
//   rowcnt         :    65,536
//   aidx           :    65,536
// ---------------------------------------------------------------------------
#define OFF_SKT    0
#define OFF_REFT   8388608
#define OFF_ISN    16777216
#define OFF_IR     16842752
#define OFF_SSUM   16908288
#define OFF_DIAG   17170432
#define OFF_ROWSUM 17235968
#define OFF_ROWCNT 17301504
#define OFF_AIDX   17367040

// ------------- convert+transpose both tensors + column sumsq partials ------
// blockIdx: x = b*16 + mchunk, y = c-half (128 ch), z = tensor (0=sketch)
__global__ __launch_bounds__(256) void convert_kernel(
    const float* __restrict__ sketch, const float* __restrict__ ref,
    short* __restrict__ sketchT, short* __restrict__ refT,
    float* __restrict__ ssum)
{
    const int b  = blockIdx.x >> 4;
    const int m  = (blockIdx.x & 15) * 256 + threadIdx.x;
    const int ch = blockIdx.y;              // 0..1
    const int z  = blockIdx.z;

    const float* src = (z ? ref : sketch) + ((size_t)(b * C_ + ch * 128)) * M_ + m;
    short* dst = (z ? refT : sketchT) + ((size_t)(b * M_ + m)) * C_ + ch * 128;

    float ss = 0.f;
#pragma unroll
    for (int j8 = 0; j8 < 16; ++j8) {
        bf16x8 v;
#pragma unroll
        for (int e = 0; e < 8; ++e) {
            float x = src[(size_t)(j8 * 8 + e) * M_];
            ss += x * x;
            v[e] = f2bf(x);
        }
        *reinterpret_cast<bf16x8*>(dst + j8 * 8) = v;
    }
    ssum[(size_t)(z * 2 + ch) * (B_ * M_) + b * M_ + m] = ss;
}

// ------------- norm finalize + anchor index + accumulator init -------------
__global__ __launch_bounds__(256) void finprep_kernel(
    const float* __restrict__ ssum,
    const int* __restrict__ ay, const int* __restrict__ ax,
    float* __restrict__ isn, float* __restrict__ ir,
    int* __restrict__ aidx, float* __restrict__ rowsum,
    int* __restrict__ rowcnt)
{
    const int i = blockIdx.x * 256 + threadIdx.x;   // b*M + m == b*N + n
    isn[i] = rsqrtf(ssum[i] + ssum[B_ * M_ + i]);
    ir[i]  = rsqrtf(ssum[2 * B_ * M_ + i] + ssum[3 * B_ * M_ + i]);
    aidx[i] = ay[i] * W_ + ax[i];
    rowsum[i] = 0.f;
    rowcnt[i] = 0;
}

// ------------------------------ MFMA GEMM + fused epilogue -----------------
// 256x256 tile, BK=64, 8 waves (512 thr, 2M x 4N), per-wave 128x64 output.
// 8-phase-style schedule: raw s_barrier (no vmcnt drain), counted vmcnt,
// per-phase {ds_read | stage-issue | barrier | MFMA x16}, setprio around MFMA.
// T2 swizzle: LDS phys k-slot = logical ^ (row&7), both sides (r5-verified).
// D map: col(n)=lane&15, row(m)=(lane>>4)*4+reg.
#define BK 64
#define NT 4   // C_/BK

__global__ __launch_bounds__(512, 2) void gemm_kernel(
    const short* __restrict__ sketchT, const short* __restrict__ refT,
    const int* __restrict__ aidx,
    const float* __restrict__ isn, const float* __restrict__ ir,
    float* __restrict__ diag, float* __restrict__ rowsum,
    int* __restrict__ rowcnt)
{
    // bijective XCD swizzle (1024 blocks, 1024%8==0): each XCD gets a
    // contiguous 128-block range = one batch's refT panel + 8 n-tiles (~3MB L2)
    const int bid = blockIdx.x + (blockIdx.y << 4) + (blockIdx.z << 8);
    const int nb  = (bid & 7) * 128 + (bid >> 3);
    const int mBase = (nb & 15) * 256;
    const int nBase = ((nb >> 4) & 15) * 256;
    const int b = nb >> 8;

    const int tid = threadIdx.x;
    const int lane = tid & 63, wv = tid >> 6;
    const int wm = (wv >> 2) * 128;       // wave m-offset (0/128)
    const int wn = (wv & 3) * 64;         // wave n-offset (0/64/128/192)
    const int l15 = lane & 15, l4 = lane >> 4;
    const int l7 = lane & 7, l8 = lane >> 3;
    const int ksw = ((l7 ^ l8) << 3);     // swizzled source k (shorts)

    __shared__ __align__(16) short Rs[2][256 * BK];   // refT (m rows), 32KB ea
    __shared__ __align__(16) short As[2][256 * BK];   // anchors (n rows)

    // per-thread global sources: chunk c covers rows wv*32+c*8 .. +8
    const short* aptr[4];
    const short* bptr[4];
#pragma unroll
    for (int c = 0; c < 4; ++c) {
        const int row = wv * 32 + c * 8 + l8;         // 0..255
        aptr[c] = refT + ((size_t)b * M_ + mBase + row) * C_ + ksw;
        bptr[c] = sketchT +
                  ((size_t)b * M_ + aidx[b * N_ + nBase + row]) * C_ + ksw;
    }

#define STAGE_CHUNK(bufi, c, koff)                                          \
    gload_lds16(aptr[c] + (koff), (char*)Rs[bufi] + (wv * 4 + (c)) * 1024); \
    gload_lds16(bptr[c] + (koff), (char*)As[bufi] + (wv * 4 + (c)) * 1024);

    f32x4 acc[8][4] = {};    // [m-frag][n-frag]
    bf16x8 pn[4][2];         // n-frags x ks, loaded at phase 0 of each K-tile

    // prologue: stage tiles 0 and 1
#pragma unroll
    for (int c = 0; c < 4; ++c) { STAGE_CHUNK(0, c, 0) }
#pragma unroll
    for (int c = 0; c < 4; ++c) { STAGE_CHUNK(1, c, BK) }
    asm volatile("s_waitcnt vmcnt(8)" ::: "memory");   // tile 0 landed
    __builtin_amdgcn_s_barrier();

#pragma unroll
    for (int t = 0; t < NT; ++t) {
        const int cur = t & 1;
        const int koff = (t + 1) * BK;    // staging offset for tile t+1
#pragma unroll
        for (int p = 0; p < 4; ++p) {
            bf16x8 pm[2][2];
#pragma unroll
            for (int m2 = 0; m2 < 2; ++m2)
#pragma unroll
                for (int ks = 0; ks < 2; ++ks) {
                    const int row = wm + (p * 2 + m2) * 16 + l15;
                    const int kph = ((ks * 4 + l4) ^ (l15 & 7)) << 3;
                    pm[m2][ks] = *reinterpret_cast<const bf16x8*>(
                        &Rs[cur][row * BK + kph]);
                }
            if (p == 0) {
#pragma unroll
                for (int nf = 0; nf < 4; ++nf)
#pragma unroll
                    for (int ks = 0; ks < 2; ++ks) {
                        const int row = wn + nf * 16 + l15;
                        const int kph = ((ks * 4 + l4) ^ (l15 & 7)) << 3;
                        pn[nf][ks] = *reinterpret_cast<const bf16x8*>(
                            &As[cur][row * BK + kph]);
                    }
            }
            if (t == 1 || t == 2) { STAGE_CHUNK(cur ^ 1, p, koff) }
            __builtin_amdgcn_s_barrier();
            __builtin_amdgcn_sched_barrier(0);
            __builtin_amdgcn_s_setprio(1);
#pragma unroll
            for (int m2 = 0; m2 < 2; ++m2)
#pragma unroll
                for (int nf = 0; nf < 4; ++nf)
#pragma unroll
                    for (int ks = 0; ks < 2; ++ks)
                        acc[p * 2 + m2][nf] =
                            __builtin_amdgcn_mfma_f32_16x16x32_bf16(
                                pm[m2][ks], pn[nf][ks],
                                acc[p * 2 + m2][nf], 0, 0, 0);
            __builtin_amdgcn_s_setprio(0);
            if (p < 3) __builtin_amdgcn_s_barrier();
        }
        if (t < NT - 1) {
            // tile t+1's loads (8/thread) must be fully landed and visible
            // to ALL waves before next iteration's ds_reads: own-drain + bar.
            asm volatile("s_waitcnt vmcnt(0)" ::: "memory");
            __builtin_amdgcn_s_barrier();
        }
    }
#undef STAGE_CHUNK

    // epilogue: sim = dot * isn[aidx[n]] * ir[m]; diag store + relu mining
    float irv[8][4];
#pragma unroll
    for (int mf = 0; mf < 8; ++mf)
#pragma unroll
        for (int r = 0; r < 4; ++r)
            irv[mf][r] = ir[b * M_ + mBase + wm + mf * 16 + l4 * 4 + r];

#pragma unroll
    for (int nf = 0; nf < 4; ++nf) {
        const int gn = nBase + wn + nf * 16 + l15;
        const float ian = isn[b * M_ + aidx[b * N_ + gn]];
        float s = 0.f; int cnt = 0;
#pragma unroll
        for (int mf = 0; mf < 8; ++mf) {
#pragma unroll
            for (int r = 0; r < 4; ++r) {
                const int gm = mBase + wm + mf * 16 + l4 * 4 + r;
                const float sim = acc[mf][nf][r] * irv[mf][r] * ian;
                if (gm == gn) {
                    diag[b * N_ + gn] = 1.0f - sim;       // unique producer
                } else if (sim > THRESH_) {
                    s += sim - THRESH_; ++cnt;            // ~never fires
                }
            }
        }
        if (cnt) {
            atomicAdd(&rowsum[b * N_ + gn], s);
            atomicAdd(&rowcnt[b * N_ + gn], cnt);
        }
    }
}

// -------- exact top-4 recompute for overfull rows (empty for this input) ---
__global__ __launch_bounds__(256) void fallback_kernel(
    const short* __restrict__ sketchT, const short* __restrict__ refT,
    const int* __restrict__ aidx,
    const float* __restrict__ isn, const float* __restrict__ ir,
    const int* __restrict__ rowcnt, float* __restrict__ rowsum)
{
    __shared__ float av[C_];
    __shared__ float tops[256][4];
    for (int row = blockIdx.x; row < B_ * N_; row += gridDim.x) {
        if (rowcnt[row] <= 4) continue;               // block-uniform branch
        const int b = row >> 12, n = row & (N_ - 1);
        const int an = aidx[row];
        __syncthreads();
        av[threadIdx.x] = bf2f(sketchT[((size_t)b * M_ + an) * C_ + threadIdx.x]);
        __syncthreads();
        const float ian = isn[b * M_ + an];
        float t0 = 0, t1 = 0, t2 = 0, t3 = 0;   // descending top-4 relu vals
        for (int m = threadIdx.x; m < M_; m += 256) {
            if (m == n) continue;
            const short* rp = refT + ((size_t)b * M_ + m) * C_;
            float dot = 0.f;
#pragma unroll 8
            for (int c = 0; c < C_; ++c) dot += av[c] * bf2f(rp[c]);
            float rl = dot * ian * ir[b * M_ + m] - THRESH_;
            if (rl > t3) {
                t3 = rl;
                if (t3 > t2) { float t = t2; t2 = t3; t3 = t; }
                if (t2 > t1) { float t = t1; t1 = t2; t2 = t; }
                if (t1 > t0) { float t = t0; t0 = t1; t1 = t; }
            }
        }
        tops[threadIdx.x][0] = t0; tops[threadIdx.x][1] = t1;
        tops[threadIdx.x][2] = t2; tops[threadIdx.x][3] = t3;
        __syncthreads();
        if (threadIdx.x == 0) {
            float s0 = 0, s1 = 0, s2 = 0, s3 = 0;
            for (int t = 0; t < 1024; ++t) {
                float v = tops[t >> 2][t & 3];
                if (v > s3) {
                    s3 = v;
                    if (s3 > s2) { float tt = s2; s2 = s3; s3 = tt; }
                    if (s2 > s1) { float tt = s1; s1 = s2; s2 = tt; }
                    if (s1 > s0) { float tt = s0; s0 = s1; s1 = tt; }
                }
            }
            rowsum[row] = s0 + s1 + s2 + s3;   // exact top-4 sum overrides
        }
        __syncthreads();
    }
}

// ------------------------------ final reduce -------------------------------
__global__ __launch_bounds__(256) void final_kernel(
    const float* __restrict__ rowsum, const float* __restrict__ diag,
    float* __restrict__ out)
{
    float sn = 0.f, sp = 0.f;
    for (int i = threadIdx.x; i < B_ * N_; i += 256) {
        sn += rowsum[i];
        sp += diag[i];
    }
    __shared__ float red[256];
    red[threadIdx.x] = sp * (1.0f / (B_ * N_)) + sn * (1.0f / (B_ * N_ * 4));
    __syncthreads();
    for (int s = 128; s > 0; s >>= 1) {
        if (threadIdx.x < s) red[threadIdx.x] += red[threadIdx.x + s];
        __syncthreads();
    }
    if (threadIdx.x == 0) out[0] = red[0];
}

// ---------------------------------------------------------------------------
extern "C" void kernel_launch(void* const* d_in, const int* in_sizes, int n_in,
                              void* d_out, int out_size, void* d_ws, size_t ws_size,
                              hipStream_t stream)
{
    const float* sketch = (const float*)d_in[0];
    const float* ref    = (const float*)d_in[1];
    const int*   ay     = (const int*)d_in[2];
    const int*   ax     = (const int*)d_in[3];
    float* out = (float*)d_out;

    char* ws = (char*)d_ws;
    short* sketchT  = (short*)(ws + OFF_SKT);
    short* refT     = (short*)(ws + OFF_REFT);
    float* isn      = (float*)(ws + OFF_ISN);
    float* ir       = (float*)(ws + OFF_IR);
    float* ssum     = (float*)(ws + OFF_SSUM);
    float* diag     = (float*)(ws + OFF_DIAG);
    float* rowsum   = (float*)(ws + OFF_ROWSUM);
    int*   rowcnt   = (int*)(ws + OFF_ROWCNT);
    int*   aidx     = (int*)(ws + OFF_AIDX);

    convert_kernel<<<dim3(16 * B_, 2, 2), 256, 0, stream>>>(
        sketch, ref, sketchT, refT, ssum);
    finprep_kernel<<<(B_ * M_) / 256, 256, 0, stream>>>(
        ssum, ay, ax, isn, ir, aidx, rowsum, rowcnt);

    gemm_kernel<<<dim3(16, 16, 4), 512, 0, stream>>>(
        sketchT, refT, aidx, isn, ir, diag, rowsum, rowcnt);

    fallback_kernel<<<64, 256, 0, stream>>>(sketchT, refT, aidx, isn, ir,
                                            rowcnt, rowsum);
    final_kernel<<<1, 256, 0, stream>>>(rowsum, diag, out);
}

// Round 10
// 147.477 us; speedup vs baseline: 1.4641x; 1.4641x over previous
//
#include <hip/hip_runtime.h>
#include <math.h>

// Problem constants (fixed by setup_inputs)
#define B_  4
#define C_  256
#define W_  64
#define M_  4096          // ref locations (H*W)
#define N_  4096          // anchors per batch (== M_)
#define THRESH_ 0.4f      // relu(0.6 - dist) = relu(sim - 0.4)

typedef __attribute__((ext_vector_type(8))) short bf16x8;
typedef __attribute__((ext_vector_type(4))) float f32x4;

__device__ __forceinline__ short f2bf(float x) {       // RNE float->bf16
    union { float f; unsigned u; } v; v.f = x;
    unsigned r = v.u + 0x7fffu + ((v.u >> 16) & 1u);
    return (short)(r >> 16);
}
__device__ __forceinline__ float bf2f(short s) {
    union { unsigned u; float f; } v;
    v.u = ((unsigned)(unsigned short)s) << 16;
    return v.f;
}
__device__ __forceinline__ void gload_lds16(const void* g, void* l) {
    __builtin_amdgcn_global_load_lds(
        (const __attribute__((address_space(1))) void*)g,
        (__attribute__((address_space(3))) void*)l, 16, 0, 0);
}

// ---------------------------------------------------------------------------
// Workspace layout (bytes); max end 17,432,576 == r5-proven bound.
//   sketchT (bf16) : 8,388,608   [b][m][c]
//   refT    (bf16) : 8,388,608   [b][m][c]
//   isn / ir       : 65,536 each
//   flagcnt/flaglist: prep-scratch region
//   diag / rowsum / rowcnt / aidx : 65,536 each
// ---------------------------------------------------------------------------
#define OFF_SKT    0
#define OFF_REFT   8388608
#define OFF_ISN    16777216
#define OFF_IR     16842752
#define OFF_FLAGC  16908288
#define OFF_FLAGL  16908544            // ends 16,974,080
#define OFF_DIAG   17170432
#define OFF_ROWSUM 17235968
#define OFF_ROWCNT 17301504
#define OFF_AIDX   17367040

// ---------- fused convert+transpose+norm+init (LDS-tiled) ------------------
// block = (b, 64-row m-tile) x (z: 0=sketch,1=ref). Reads float4 coalesced
// along m; bf16 tile [64][256] in LDS with chunk-XOR swizzle
// phys = ch ^ ((row>>2)&7): write-side 4-way max (key varies with lane&7;
// bank = 4*(phys&7)+(off>>1)), read-out conflict-free (row-uniform key,
// ch bijective across lanes). Write-out fully coalesced (contiguous 32KB).
// Full c-range in-block -> column norms finalize here (no ssum pass).
#define RS_ 256   // tile row stride (shorts)

__global__ __launch_bounds__(256) void convert_kernel(
    const float* __restrict__ sketch, const float* __restrict__ ref,
    short* __restrict__ sketchT, short* __restrict__ refT,
    const int* __restrict__ ay, const int* __restrict__ ax,
    float* __restrict__ isn, float* __restrict__ ir,
    int* __restrict__ aidx, float* __restrict__ rowsum,
    int* __restrict__ rowcnt, int* __restrict__ flagcnt)
{
    const int z  = blockIdx.y;
    const int b  = blockIdx.x >> 6;
    const int m0 = (blockIdx.x & 63) * 64;
    const int tid = threadIdx.x;
    const int lane = tid & 63, wv = tid >> 6;
    const int lg = lane >> 4;            // c-subgroup 0..3
    const int mloc = (lane & 15) * 4;    // local m base (4 rows per lane)
    const int key = lane & 7;            // == ((mloc+e)>>2)&7 for e<4

    __shared__ __align__(16) short Ts[64 * RS_];   // 32KB bf16 tile [m][c]
    __shared__ float ssp[4][64];

    const float* src = (z ? ref : sketch) + (size_t)b * C_ * M_ + m0 + mloc;
    float s0 = 0.f, s1 = 0.f, s2 = 0.f, s3 = 0.f;
#pragma unroll
    for (int i = 0; i < 16; ++i) {
        const int cc = wv * 64 + i * 4 + lg;
        const float4 v = *reinterpret_cast<const float4*>(src + (size_t)cc * M_);
        s0 += v.x * v.x; s1 += v.y * v.y; s2 += v.z * v.z; s3 += v.w * v.w;
        const int ch = cc >> 3, off = cc & 7;
        const int ph = ((ch ^ key) << 3) | off;
        Ts[(mloc + 0) * RS_ + ph] = f2bf(v.x);
        Ts[(mloc + 1) * RS_ + ph] = f2bf(v.y);
        Ts[(mloc + 2) * RS_ + ph] = f2bf(v.z);
        Ts[(mloc + 3) * RS_ + ph] = f2bf(v.w);
    }
    // sum over the 4 c-subgroups (lane bits 4-5): xor-16/32 butterfly
    s0 += __shfl_xor(s0, 16); s0 += __shfl_xor(s0, 32);
    s1 += __shfl_xor(s1, 16); s1 += __shfl_xor(s1, 32);
    s2 += __shfl_xor(s2, 16); s2 += __shfl_xor(s2, 32);
    s3 += __shfl_xor(s3, 16); s3 += __shfl_xor(s3, 32);
    if (lane < 16) {
        ssp[wv][mloc + 0] = s0; ssp[wv][mloc + 1] = s1;
        ssp[wv][mloc + 2] = s2; ssp[wv][mloc + 3] = s3;
    }
    if (z == 0 && blockIdx.x == 0 && tid == 64) *flagcnt = 0;
    __syncthreads();

    if (tid < 64) {
        const float tot = ssp[0][tid] + ssp[1][tid] + ssp[2][tid] + ssp[3][tid];
        const int gi = b * M_ + m0 + tid;
        if (z == 0) {
            isn[gi] = rsqrtf(tot);
            aidx[gi] = ay[gi] * W_ + ax[gi];
            rowsum[gi] = 0.f;
            rowcnt[gi] = 0;
        } else {
            ir[gi] = rsqrtf(tot);
        }
    }

    // write-out: whole tile is contiguous 32KB; thread t writes 16B chunks
    short* dst = (z ? refT : sketchT) + ((size_t)b * M_ + m0) * C_;
#pragma unroll
    for (int it = 0; it < 8; ++it) {
        const int g = it * 256 + tid;
        const int r = g >> 5, ch = g & 31;
        const bf16x8 v = *reinterpret_cast<const bf16x8*>(
            &Ts[r * RS_ + ((ch ^ ((r >> 2) & 7)) << 3)]);
        *reinterpret_cast<bf16x8*>(dst + g * 8) = v;
    }
}

// ------------------------------ MFMA GEMM + fused epilogue -----------------
// 256x256 tile, BK=64, 8 waves (512 thr, 2M x 4N), per-wave 128x64 output.
// Raw s_barrier (no vmcnt drain), counted vmcnt, per-phase
// {ds_read | stage-issue | barrier | MFMA x16}, setprio around MFMA.
// T2 swizzle: LDS phys k-slot = logical ^ (row&7), both sides (r5-verified).
// D map: col(n)=lane&15, row(m)=(lane>>4)*4+reg.  [HW-proven: r8 absmax 0.0]
#define BK 64
#define NT 4   // C_/BK

__global__ __launch_bounds__(512, 2) void gemm_kernel(
    const short* __restrict__ sketchT, const short* __restrict__ refT,
    const int* __restrict__ aidx,
    const float* __restrict__ isn, const float* __restrict__ ir,
    float* __restrict__ diag, float* __restrict__ rowsum,
    int* __restrict__ rowcnt)
{
    // bijective XCD swizzle (1024 blocks, 1024%8==0)
    const int bid = blockIdx.x + (blockIdx.y << 4) + (blockIdx.z << 8);
    const int nb  = (bid & 7) * 128 + (bid >> 3);
    const int mBase = (nb & 15) * 256;
    const int nBase = ((nb >> 4) & 15) * 256;
    const int b = nb >> 8;

    const int tid = threadIdx.x;
    const int lane = tid & 63, wv = tid >> 6;
    const int wm = (wv >> 2) * 128;       // wave m-offset (0/128)
    const int wn = (wv & 3) * 64;         // wave n-offset (0/64/128/192)
    const int l15 = lane & 15, l4 = lane >> 4;
    const int l7 = lane & 7, l8 = lane >> 3;
    const int ksw = ((l7 ^ l8) << 3);     // swizzled source k (shorts)

    __shared__ __align__(16) short Rs[2][256 * BK];   // refT (m rows)
    __shared__ __align__(16) short As[2][256 * BK];   // anchors (n rows)

    const short* aptr[4];
    const short* bptr[4];
#pragma unroll
    for (int c = 0; c < 4; ++c) {
        const int row = wv * 32 + c * 8 + l8;         // 0..255
        aptr[c] = refT + ((size_t)b * M_ + mBase + row) * C_ + ksw;
        bptr[c] = sketchT +
                  ((size_t)b * M_ + aidx[b * N_ + nBase + row]) * C_ + ksw;
    }

#define STAGE_CHUNK(bufi, c, koff)                                          \
    gload_lds16(aptr[c] + (koff), (char*)Rs[bufi] + (wv * 4 + (c)) * 1024); \
    gload_lds16(bptr[c] + (koff), (char*)As[bufi] + (wv * 4 + (c)) * 1024);

    f32x4 acc[8][4] = {};    // [m-frag][n-frag]
    bf16x8 pn[4][2];         // n-frags x ks, loaded at phase 0 of each K-tile

    // prologue: stage tiles 0 and 1
#pragma unroll
    for (int c = 0; c < 4; ++c) { STAGE_CHUNK(0, c, 0) }
#pragma unroll
    for (int c = 0; c < 4; ++c) { STAGE_CHUNK(1, c, BK) }
    asm volatile("s_waitcnt vmcnt(8)" ::: "memory");   // tile 0 landed
    __builtin_amdgcn_s_barrier();

#pragma unroll
    for (int t = 0; t < NT; ++t) {
        const int cur = t & 1;
        const int koff = (t + 1) * BK;    // staging offset for tile t+1
#pragma unroll
        for (int p = 0; p < 4; ++p) {
            bf16x8 pm[2][2];
#pragma unroll
            for (int m2 = 0; m2 < 2; ++m2)
#pragma unroll
                for (int ks = 0; ks < 2; ++ks) {
                    const int row = wm + (p * 2 + m2) * 16 + l15;
                    const int kph = ((ks * 4 + l4) ^ (l15 & 7)) << 3;
                    pm[m2][ks] = *reinterpret_cast<const bf16x8*>(
                        &Rs[cur][row * BK + kph]);
                }
            if (p == 0) {
#pragma unroll
                for (int nf = 0; nf < 4; ++nf)
#pragma unroll
                    for (int ks = 0; ks < 2; ++ks) {
                        const int row = wn + nf * 16 + l15;
                        const int kph = ((ks * 4 + l4) ^ (l15 & 7)) << 3;
                        pn[nf][ks] = *reinterpret_cast<const bf16x8*>(
                            &As[cur][row * BK + kph]);
                    }
            }
            if (t == 1 || t == 2) { STAGE_CHUNK(cur ^ 1, p, koff) }
            __builtin_amdgcn_s_barrier();
            __builtin_amdgcn_sched_barrier(0);
            __builtin_amdgcn_s_setprio(1);
#pragma unroll
            for (int m2 = 0; m2 < 2; ++m2)
#pragma unroll
                for (int nf = 0; nf < 4; ++nf)
#pragma unroll
                    for (int ks = 0; ks < 2; ++ks)
                        acc[p * 2 + m2][nf] =
                            __builtin_amdgcn_mfma_f32_16x16x32_bf16(
                                pm[m2][ks], pn[nf][ks],
                                acc[p * 2 + m2][nf], 0, 0, 0);
            __builtin_amdgcn_s_setprio(0);
            if (p < 3) __builtin_amdgcn_s_barrier();
        }
        if (t < NT - 1) {
            asm volatile("s_waitcnt vmcnt(0)" ::: "memory");
            __builtin_amdgcn_s_barrier();
        }
    }
#undef STAGE_CHUNK

    // epilogue: sim = dot * isn[aidx[n]] * ir[m]; diag store + relu mining
    float irv[8][4];
#pragma unroll
    for (int mf = 0; mf < 8; ++mf)
#pragma unroll
        for (int r = 0; r < 4; ++r)
            irv[mf][r] = ir[b * M_ + mBase + wm + mf * 16 + l4 * 4 + r];

#pragma unroll
    for (int nf = 0; nf < 4; ++nf) {
        const int gn = nBase + wn + nf * 16 + l15;
        const float ian = isn[b * M_ + aidx[b * N_ + gn]];
        float s = 0.f; int cnt = 0;
#pragma unroll
        for (int mf = 0; mf < 8; ++mf) {
#pragma unroll
            for (int r = 0; r < 4; ++r) {
                const int gm = mBase + wm + mf * 16 + l4 * 4 + r;
                const float sim = acc[mf][nf][r] * irv[mf][r] * ian;
                if (gm == gn) {
                    diag[b * N_ + gn] = 1.0f - sim;       // unique producer
                } else if (sim > THRESH_) {
                    s += sim - THRESH_; ++cnt;            // ~never fires
                }
            }
        }
        if (cnt) {
            atomicAdd(&rowsum[b * N_ + gn], s);
            atomicAdd(&rowcnt[b * N_ + gn], cnt);
        }
    }
}

// ------------------------- flag rows needing exact top-4 -------------------
// parallel coalesced scan + compaction (r5-proven; ~2us)
__global__ __launch_bounds__(256) void flag_kernel(
    const int* __restrict__ rowcnt, int* __restrict__ flagcnt,
    int* __restrict__ flaglist)
{
    int i = blockIdx.x * 256 + threadIdx.x;   // b*N + n
    if (rowcnt[i] > 4) {
        int p = atomicAdd(flagcnt, 1);
        flaglist[p] = i;
    }
}

// -------- exact top-4 recompute for flagged rows (empty for this input) ----
__global__ __launch_bounds__(256) void fallback_kernel(
    const short* __restrict__ sketchT, const short* __restrict__ refT,
    const int* __restrict__ aidx,
    const float* __restrict__ isn, const float* __restrict__ ir,
    const int* __restrict__ flagcnt, const int* __restrict__ flaglist,
    float* __restrict__ rowsum)
{
    const int nflag = *flagcnt;
    __shared__ float av[C_];
    __shared__ float tops[256][4];
    for (int fi = blockIdx.x; fi < nflag; fi += gridDim.x) {
        const int row = flaglist[fi];
        const int b = row >> 12, n = row & (N_ - 1);
        const int an = aidx[row];
        __syncthreads();
        av[threadIdx.x] = bf2f(sketchT[((size_t)b * M_ + an) * C_ + threadIdx.x]);
        __syncthreads();
        const float ian = isn[b * M_ + an];
        float t0 = 0, t1 = 0, t2 = 0, t3 = 0;   // descending top-4 relu vals
        for (int m = threadIdx.x; m < M_; m += 256) {
            if (m == n) continue;
            const short* rp = refT + ((size_t)b * M_ + m) * C_;
            float dot = 0.f;
#pragma unroll 8
            for (int c = 0; c < C_; ++c) dot += av[c] * bf2f(rp[c]);
            float rl = dot * ian * ir[b * M_ + m] - THRESH_;
            if (rl > t3) {
                t3 = rl;
                if (t3 > t2) { float t = t2; t2 = t3; t3 = t; }
                if (t2 > t1) { float t = t1; t1 = t2; t2 = t; }
                if (t1 > t0) { float t = t0; t0 = t1; t1 = t; }
            }
        }
        tops[threadIdx.x][0] = t0; tops[threadIdx.x][1] = t1;
        tops[threadIdx.x][2] = t2; tops[threadIdx.x][3] = t3;
        __syncthreads();
        if (threadIdx.x == 0) {
            float s0 = 0, s1 = 0, s2 = 0, s3 = 0;
            for (int t = 0; t < 1024; ++t) {
                float v = tops[t >> 2][t & 3];
                if (v > s3) {
                    s3 = v;
                    if (s3 > s2) { float tt = s2; s2 = s3; s3 = tt; }
                    if (s2 > s1) { float tt = s1; s1 = s2; s2 = tt; }
                    if (s1 > s0) { float tt = s0; s0 = s1; s1 = tt; }
                }
            }
            rowsum[row] = s0 + s1 + s2 + s3;   // exact top-4 sum overrides
        }
        __syncthreads();
    }
}

// ------------------------------ final reduce -------------------------------
__global__ __launch_bounds__(256) void final_kernel(
    const float* __restrict__ rowsum, const float* __restrict__ diag,
    float* __restrict__ out)
{
    float sn = 0.f, sp = 0.f;
    for (int i = threadIdx.x; i < B_ * N_; i += 256) {
        sn += rowsum[i];
        sp += diag[i];
    }
    __shared__ float red[256];
    red[threadIdx.x] = sp * (1.0f / (B_ * N_)) + sn * (1.0f / (B_ * N_ * 4));
    __syncthreads();
    for (int s = 128; s > 0; s >>= 1) {
        if (threadIdx.x < s) red[threadIdx.x] += red[threadIdx.x + s];
        __syncthreads();
    }
    if (threadIdx.x == 0) out[0] = red[0];
}

// ---------------------------------------------------------------------------
extern "C" void kernel_launch(void* const* d_in, const int* in_sizes, int n_in,
                              void* d_out, int out_size, void* d_ws, size_t ws_size,
                              hipStream_t stream)
{
    const float* sketch = (const float*)d_in[0];
    const float* ref    = (const float*)d_in[1];
    const int*   ay     = (const int*)d_in[2];
    const int*   ax     = (const int*)d_in[3];
    float* out = (float*)d_out;

    char* ws = (char*)d_ws;
    short* sketchT  = (short*)(ws + OFF_SKT);
    short* refT     = (short*)(ws + OFF_REFT);
    float* isn      = (float*)(ws + OFF_ISN);
    float* ir       = (float*)(ws + OFF_IR);
    int*   flagcnt  = (int*)(ws + OFF_FLAGC);
    int*   flaglist = (int*)(ws + OFF_FLAGL);
    float* diag     = (float*)(ws + OFF_DIAG);
    float* rowsum   = (float*)(ws + OFF_ROWSUM);
    int*   rowcnt   = (int*)(ws + OFF_ROWCNT);
    int*   aidx     = (int*)(ws + OFF_AIDX);

    convert_kernel<<<dim3(64 * B_, 2), 256, 0, stream>>>(
        sketch, ref, sketchT, refT, ay, ax, isn, ir, aidx,
        rowsum, rowcnt, flagcnt);

    gemm_kernel<<<dim3(16, 16, 4), 512, 0, stream>>>(
        sketchT, refT, aidx, isn, ir, diag, rowsum, rowcnt);

    flag_kernel<<<(B_ * N_) / 256, 256, 0, stream>>>(rowcnt, flagcnt, flaglist);
    fallback_kernel<<<64, 256, 0, stream>>>(sketchT, refT, aidx, isn, ir,
                                            flagcnt, flaglist, rowsum);
    final_kernel<<<1, 256, 0, stream>>>(rowsum, diag, out);
}